// Round 16
// baseline (406.681 us; speedup 1.0000x reference)
//
#include <hip/hip_runtime.h>
#include <hip/hip_bf16.h>

typedef unsigned short u16;
typedef unsigned int u32;
typedef unsigned long long u64;
typedef __attribute__((ext_vector_type(8))) short short8;
typedef __attribute__((ext_vector_type(8))) _Float16 half8;
typedef __attribute__((ext_vector_type(4))) float floatx4;
typedef __attribute__((ext_vector_type(16))) float floatx16;

#define NP 16384
#define FD 64
#define FLT_BIG 3.0e38f
#define CB 12           // flush threshold (R16: 8->12, fewer flush calls)
#define CBD 16          // candidate depth (check every 4 pairs: max idx 15)
#define CHUNK 128       // staged columns per chunk

__device__ __forceinline__ float blo(u32 u) {
  u32 v = u << 16; float f; __builtin_memcpy(&f, &v, 4); return f;
}
__device__ __forceinline__ float bhi(u32 u) {
  u32 v = u & 0xffff0000u; float f; __builtin_memcpy(&f, &v, 4); return f;
}
__device__ __forceinline__ float bf2f(u16 u) {
  u32 v = ((u32)u) << 16; float f; __builtin_memcpy(&f, &v, 4); return f;
}
__device__ __forceinline__ u16 f2bf(float f) {
  u32 u; __builtin_memcpy(&u, &f, 4);
  u += 0x7fffu + ((u >> 16) & 1u);
  return (u16)(u >> 16);
}

// runtime input-dtype sniff (confirmed fp32 in earlier rounds; kept for safety)
__device__ __forceinline__ bool sniff_bf16(const void* xg) {
  const u16* p = (const u16*)xg;
  int bad = 0;
#pragma unroll
  for (int t = 0; t < 32; ++t) {
    int e = (p[2 * t] >> 7) & 0xFF;
    bad += (e < 90 || e > 132) ? 1 : 0;
  }
  return bad <= 3;
}

// insert v (known < d[15]) into ascending-sorted 16-array, stable (earlier wins ties)
__device__ __forceinline__ void insert16(float (&d)[16], int (&id)[16], float v, int j) {
#pragma unroll
  for (int t = 15; t >= 1; --t) {
    float a = d[t-1], b = d[t];
    int   ia = id[t-1], ib = id[t];
    bool sh   = v < a;
    bool here = v < b;
    d[t]  = sh ? a  : (here ? v : b);
    id[t] = sh ? ia : (here ? j : ib);
  }
  bool h0 = v < d[0];
  d[0]  = h0 ? v : d[0];
  id[0] = h0 ? j : id[0];
}

// direct global->LDS async copies (dest = wave-uniform base + lane*size).
typedef const __attribute__((address_space(1))) u32 as1_u32;
typedef __attribute__((address_space(3))) u32 as3_u32;
__device__ __forceinline__ void async16(const void* g, void* l) {
  __builtin_amdgcn_global_load_lds((as1_u32*)(u64)g, (as3_u32*)(u32)(u64)l, 16, 0, 0);
}
__device__ __forceinline__ void async4(const void* g, void* l) {
  __builtin_amdgcn_global_load_lds((as1_u32*)(u64)g, (as3_u32*)(u32)(u64)l, 4, 0, 0);
}

// ============ workspace layout (d_ws) ============
// sqh[NP] f16 | sql[NP] f16 | xh[NP*64] f16 | xl[NP*64] f16   (4.0625 MB)
// xh = f16(x); xl = f16((x - xh) * 4096)   (scaled-lo split, near-fp32 dots)
// sqh/sql: same split of the squared norms (folded into MFMA as an extra K-slice).

// ================= K0: convert + norms =================
template<bool BF>
__device__ __forceinline__ void cvt_body(const void* x, u16* sqh, u16* sql,
                                         u16* xh, u16* xl) {
  int t = blockIdx.x * 256 + threadIdx.x;
  int row = t >> 3;
  int e0 = (t & 7) * 8;
  float v[8];
  if (BF) {
    uint4 u = *(const uint4*)((const u16*)x + (size_t)row * FD + e0);
    v[0] = blo(u.x); v[1] = bhi(u.x);
    v[2] = blo(u.y); v[3] = bhi(u.y);
    v[4] = blo(u.z); v[5] = bhi(u.z);
    v[6] = blo(u.w); v[7] = bhi(u.w);
  } else {
    const float4* p = (const float4*)((const float*)x + (size_t)row * FD + e0);
    float4 a = p[0], b = p[1];
    v[0] = a.x; v[1] = a.y; v[2] = a.z; v[3] = a.w;
    v[4] = b.x; v[5] = b.y; v[6] = b.z; v[7] = b.w;
  }
  short8 hv, lv;
  float s = 0.f;
#pragma unroll
  for (int j = 0; j < 8; ++j) {
    _Float16 h = (_Float16)v[j];
    float hf = (float)h;
    _Float16 w2 = (_Float16)((v[j] - hf) * 4096.f);
    u16 hb, lb;
    __builtin_memcpy(&hb, &h, 2);
    __builtin_memcpy(&lb, &w2, 2);
    hv[j] = (short)hb; lv[j] = (short)lb;
    s = fmaf(v[j], v[j], s);
  }
  *(short8*)(xh + (size_t)row * FD + e0) = hv;
  *(short8*)(xl + (size_t)row * FD + e0) = lv;
  s += __shfl_xor(s, 1);
  s += __shfl_xor(s, 2);
  s += __shfl_xor(s, 4);
  if ((t & 7) == 0) {
    _Float16 h = (_Float16)s;
    float hf = (float)h;
    _Float16 w2 = (_Float16)((s - hf) * 4096.f);
    u16 hb, lb;
    __builtin_memcpy(&hb, &h, 2);
    __builtin_memcpy(&lb, &w2, 2);
    sqh[row] = hb; sql[row] = lb;
  }
}
__global__ __launch_bounds__(256) void cvt_kernel(const void* x, u16* sqh, u16* sql,
                                                  u16* xh, u16* xl) {
  if (sniff_bf16(x)) cvt_body<true>(x, sqh, sql, xh, xl);
  else               cvt_body<false>(x, sqh, sql, xh, xl);
}

// flush candidate buffer: wave-max bounded runtime loop (compact code, 1 insert16 copy)
__device__ __forceinline__ void flushbuf(float2* myb, int& cnt,
                                         float (&d16)[16], int (&i16)[16]) {
  int mx = cnt;
#pragma unroll
  for (int o = 1; o < 64; o <<= 1) {
    int om = __shfl_xor(mx, o);
    mx = mx > om ? mx : om;
  }
#pragma unroll 1
  for (int e = 0; e < mx; ++e) {
    float2 v = myb[e * 64];
    float dv = (e < cnt) ? v.x : FLT_BIG;
    if (dv < d16[15]) insert16(d16, i16, dv, __float_as_int(v.y));
  }
  cnt = 0;
}

// selection epilogue for one 32x32 tile; SELF=true only for the diagonal tile
// (wave-row-base == tile-col-base; both 32-aligned so others can't contain self).
// Push is UNCONDITIONAL ds_write to slot cnt (LDS pipe, 2-way bank = free) with
// cnt += p — removes the exec-mask predication from the VALU ledger; non-pushed
// slots are overwritten by the next pair, flush guards with (e < cnt).
template<bool SELF>
__device__ __forceinline__ void epi(const floatx16& acc1, const floatx16& a2a,
                                    const floatx16& a2b, int cb0, int row,
                                    float2* myb, int& cnt,
                                    float (&d16)[16], int (&i16)[16]) {
#pragma unroll
  for (int k = 0; k < 4; ++k) {
#pragma unroll
    for (int r = 0; r < 4; ++r) {
      int t = 4 * k + r;
      // dd = sq_j/2 - dot  (monotone in distance; sq_i dropped as row-constant)
      float d = fmaf(a2a[t] + a2b[t], -2.44140625e-4f, -acc1[t]);
      int col = cb0 + r + 8 * k;
      bool p = (d < d16[15]);
      if (SELF) p = p & (col != row);
      myb[cnt * 64] = make_float2(d, __int_as_float(col));  // unconditional
      cnt += p;
    }
    if (__any(cnt >= CB)) flushbuf(myb, cnt, d16, i16);   // max idx 15 < depth
  }
}

// ======== K1: 4-seg MFMA kNN (R7/R12/R15-proven structure). grid (NP/128, 4) ========
// Per wave: 32 rows; B = row points (regs), A = column points (LDS, 128-col chunks,
// two-barrier staging).  3 MFMA chains (hh+sq -> acc1; h*lo+sql -> a2a; lo*h -> a2b).
// C layout: col=lane&31 -> ROW point; row=(reg&3)+8*(reg>>2)+4*(lane>>5) -> col point.
// LDS k-slot swizzle kc^(col&7) applied on the global source (linear LDS dest).
// launch_bounds(256,2): LDS (64.5KB) caps at 2 blocks/CU anyway -> big VGPR budget;
// unroll 2 of the ct-tiles (R12-proven, 92 VGPR): MFMA chains of tile ct+1 overlap
// epi/flush VALU of tile ct.  (Full unroll = compile blowup, R13/R14.)
__global__ __launch_bounds__(256, 2) void knn_kernel(
    const u16* __restrict__ xh, const u16* __restrict__ xl,
    const u16* __restrict__ sqh, const u16* __restrict__ sql,
    float* __restrict__ outf) {
  __shared__ u16 ch[CHUNK * 64];      // 16 KB  hi chunk (swizzled slots)
  __shared__ u16 cl[CHUNK * 64];      // 16 KB  lo chunk
  __shared__ u16 sqhl[CHUNK];         // 256 B
  __shared__ u16 sqll[CHUNK];         // 256 B
  __shared__ float2 cbuf[4][CBD][64]; // 32 KB  candidate buffers

  int tid = threadIdx.x;
  int w = __builtin_amdgcn_readfirstlane(tid >> 6);
  int l = tid & 63;
  int lo5 = l & 31, hi5 = l >> 5;
  int row = blockIdx.x * 128 + w * 32 + lo5;
  int rowbase = blockIdx.x * 128 + w * 32;
  int seg0 = blockIdx.y * 4096;

  half8 bh[4], bl[4];
  {
    const u16* rp = xh + (size_t)row * FD + hi5 * 8;
    const u16* rq = xl + (size_t)row * FD + hi5 * 8;
#pragma unroll
    for (int q = 0; q < 4; ++q) {
      bh[q] = *(const half8*)(rp + q * 16);
      bl[q] = *(const half8*)(rq + q * 16);
    }
  }
  half8 bx;
#pragma unroll
  for (int j = 0; j < 8; ++j) bx[j] = (_Float16)0.f;
  if (hi5 == 0) bx[0] = (_Float16)(-0.5f);

  float d16[16]; int i16[16];
#pragma unroll
  for (int t = 0; t < 16; ++t) { d16[t] = FLT_BIG; i16[t] = 0; }
  float2* myb = &cbuf[w][0][l];
  int cnt = 0;

#pragma unroll 1
  for (int c = 0; c < 4096 / CHUNK; ++c) {
    int colbase = seg0 + c * CHUNK;
    __syncthreads();
#pragma unroll
    for (int u = 0; u < 4; ++u) {
      int s = (u * 4 + w) * 64 + l;
      int col = s >> 3, kc = s & 7;
      int off = ((colbase + col) << 6) + ((kc ^ (col & 7)) << 3);
      async16(xh + off, &ch[(u * 4 + w) * 512]);
      async16(xl + off, &cl[(u * 4 + w) * 512]);
    }
    if (w == 0) {
      async4((const u32*)(sqh + colbase) + l, &sqhl[0]);
      async4((const u32*)(sql + colbase) + l, &sqll[0]);
    }
    __syncthreads();

#pragma unroll 2
    for (int ct = 0; ct < CHUNK / 32; ++ct) {
      int colA = ct * 32 + lo5;
      int c7 = colA & 7;
      const u16* hp = &ch[colA * 64];
      const u16* lp = &cl[colA * 64];

      half8 ax, axl;
#pragma unroll
      for (int j = 0; j < 8; ++j) { ax[j] = (_Float16)0.f; axl[j] = (_Float16)0.f; }
      {
        u16 shv = sqhl[colA], slv = sqll[colA];
        _Float16 fh, fl2;
        __builtin_memcpy(&fh, &shv, 2);
        __builtin_memcpy(&fl2, &slv, 2);
        if (hi5 == 0) { ax[0] = fh; axl[0] = fl2; }
      }
      floatx16 zz;
#pragma unroll
      for (int t = 0; t < 16; ++t) zz[t] = 0.f;
      floatx16 acc1 = __builtin_amdgcn_mfma_f32_32x32x16_f16(ax,  bx, zz, 0, 0, 0);
      floatx16 a2a  = __builtin_amdgcn_mfma_f32_32x32x16_f16(axl, bx, zz, 0, 0, 0);
      floatx16 a2b  = zz;
#pragma unroll
      for (int q = 0; q < 4; ++q) {
        int so = ((2 * q + hi5) ^ c7) << 3;
        half8 ah = *(const half8*)(hp + so);
        half8 al = *(const half8*)(lp + so);
        acc1 = __builtin_amdgcn_mfma_f32_32x32x16_f16(ah, bh[q], acc1, 0, 0, 0);
        a2a  = __builtin_amdgcn_mfma_f32_32x32x16_f16(ah, bl[q], a2a, 0, 0, 0);
        a2b  = __builtin_amdgcn_mfma_f32_32x32x16_f16(al, bh[q], a2b, 0, 0, 0);
      }
      int cb0 = colbase + ct * 32 + 4 * hi5;
      bool diag = (rowbase == colbase + ct * 32);
      if (diag) epi<true >(acc1, a2a, a2b, cb0, row, myb, cnt, d16, i16);
      else      epi<false>(acc1, a2a, a2b, cb0, row, myb, cnt, d16, i16);
    }
  }
  flushbuf(myb, cnt, d16, i16);

  float od[16]; int oi[16];
#pragma unroll
  for (int t = 0; t < 16; ++t) {
    od[t] = __shfl_xor(d16[t], 32);
    oi[t] = __shfl_xor(i16[t], 32);
  }
#pragma unroll
  for (int t = 0; t < 16; ++t)
    if (od[t] < d16[15]) insert16(d16, i16, od[t], oi[t]);

  if (hi5 == 0) {
    float2* op = (float2*)outf + (size_t)row * 64 + blockIdx.y * 16;
#pragma unroll
    for (int t = 0; t < 8; ++t) {
      float4 v4 = make_float4(d16[2*t],   __int_as_float(i16[2*t]),
                              d16[2*t+1], __int_as_float(i16[2*t+1]));
      *(float4*)(op + 2 * t) = v4;
    }
  }
}

// ======== K2: merge 4 segment partials -> final 16 ids (record ints [0..15]) ========
// 4 lanes per point: own seg's sorted 16 copied, then 2 shfl-merge rounds;
// seg-ascending combine preserves stable ties (strict-<).
__global__ __launch_bounds__(256) void merge_kernel(float* outf) {
  int tid = threadIdx.x;
  int p = blockIdx.x * 64 + (tid >> 2);
  int sub = tid & 3;
  const float2* cp = (const float2*)outf + (size_t)p * 64 + sub * 16;
  float d16[16]; int i16[16];
#pragma unroll
  for (int t = 0; t < 16; ++t) {
    float2 v = cp[t];
    d16[t] = v.x; i16[t] = __float_as_int(v.y);
  }
#pragma unroll
  for (int rnd = 0; rnd < 2; ++rnd) {
    int dx = 1 << rnd;
    float od[16]; int oi[16];
#pragma unroll
    for (int t = 0; t < 16; ++t) {
      od[t] = __shfl_xor(d16[t], dx);
      oi[t] = __shfl_xor(i16[t], dx);
    }
#pragma unroll
    for (int t = 0; t < 16; ++t)
      if (od[t] < d16[15]) insert16(d16, i16, od[t], oi[t]);
  }
  if (sub == 0) {
    int* op = (int*)outf + (size_t)p * 128;
#pragma unroll
    for (int t = 0; t < 16; ++t) op[t] = i16[t];
  }
}

// ================= K3: edge MLP + max aggregation (MFMA, bf16 compute) =================
// A-frag 16x16x32: lane holds A[m=l&15][k=(l>>4)*8+j].  C/D: col=l&15, row=(l>>4)*4+reg.
// grid 1024 blocks to hide the random neighbor gathers; fp32 gathers via float4.
template<bool BF>
__device__ __forceinline__ void mlp_body(
    const void* x, const void* W1, const void* b1,
    const void* W2, const void* b2, float* outf,
    short* w1f, short* w2f, short (*hbuf)[2048]) {
  int tid = threadIdx.x;
  for (int s2 = tid; s2 < 4096; s2 += 256) {
    int which = s2 >> 11, t = s2 & 2047;
    int frag = t >> 6, lane = t & 63;
    int nt = frag >> 2, kk = frag & 3;
    int n  = nt * 16 + (lane & 15);
    int kb = kk * 32 + ((lane >> 4) * 8);
    short8 v;
    if (BF) {
      const u16* W = (const u16*)(which ? W2 : W1);
#pragma unroll
      for (int j = 0; j < 8; ++j) v[j] = (short)W[(size_t)(kb + j) * 128 + n];
    } else {
      const float* W = (const float*)(which ? W2 : W1);
#pragma unroll
      for (int j = 0; j < 8; ++j) v[j] = (short)f2bf(W[(size_t)(kb + j) * 128 + n]);
    }
    *(short8*)((which ? w2f : w1f) + t * 8) = v;
  }
  __syncthreads();

  int l = tid & 63, w = tid >> 6;
  int q = l >> 4, c = l & 15;
  short* hb = hbuf[w];

  float b1v[8], b2v[8];
#pragma unroll
  for (int nt = 0; nt < 8; ++nt) {
    b1v[nt] = BF ? bf2f(((const u16*)b1)[nt * 16 + c]) : ((const float*)b1)[nt * 16 + c];
    b2v[nt] = BF ? bf2f(((const u16*)b2)[nt * 16 + c]) : ((const float*)b2)[nt * 16 + c];
  }

  int wid = blockIdx.x * 4 + w;
  for (int p = wid; p < NP; p += 4096) {
    int nb = ((const int*)outf)[(size_t)p * 128 + c] & (NP - 1);
    short8 a1[4];
    if (BF) {
      const short* xp  = (const short*)x + (size_t)p  * FD;
      const short* xnp = (const short*)x + (size_t)nb * FD;
      a1[0] = *(const short8*)(xp + q * 8);
      a1[1] = *(const short8*)(xp + 32 + q * 8);
#pragma unroll
      for (int kk = 2; kk < 4; ++kk) {
        int kb = (kk - 2) * 32 + q * 8;
        short8 xi8 = *(const short8*)(xp + kb);
        short8 xj8 = *(const short8*)(xnp + kb);
        short8 dfr;
#pragma unroll
        for (int j = 0; j < 8; ++j)
          dfr[j] = (short)f2bf(bf2f((u16)xj8[j]) - bf2f((u16)xi8[j]));
        a1[kk] = dfr;
      }
    } else {
      const float* xp  = (const float*)x + (size_t)p  * FD + q * 8;
      const float* xnp = (const float*)x + (size_t)nb * FD + q * 8;
      float4 pi0 = *(const float4*)(xp);
      float4 pi1 = *(const float4*)(xp + 4);
      float4 pj0 = *(const float4*)(xp + 32);
      float4 pj1 = *(const float4*)(xp + 36);
      float4 ni0 = *(const float4*)(xnp);
      float4 ni1 = *(const float4*)(xnp + 4);
      float4 nj0 = *(const float4*)(xnp + 32);
      float4 nj1 = *(const float4*)(xnp + 36);
      float xi0a[8] = {pi0.x, pi0.y, pi0.z, pi0.w, pi1.x, pi1.y, pi1.z, pi1.w};
      float xi1a[8] = {pj0.x, pj0.y, pj0.z, pj0.w, pj1.x, pj1.y, pj1.z, pj1.w};
      float xn0a[8] = {ni0.x, ni0.y, ni0.z, ni0.w, ni1.x, ni1.y, ni1.z, ni1.w};
      float xn1a[8] = {nj0.x, nj0.y, nj0.z, nj0.w, nj1.x, nj1.y, nj1.z, nj1.w};
#pragma unroll
      for (int j = 0; j < 8; ++j) {
        a1[0][j] = (short)f2bf(xi0a[j]);
        a1[1][j] = (short)f2bf(xi1a[j]);
        a1[2][j] = (short)f2bf(xn0a[j] - xi0a[j]);
        a1[3][j] = (short)f2bf(xn1a[j] - xi1a[j]);
      }
    }

#pragma unroll
    for (int nt = 0; nt < 8; ++nt) {
      floatx4 acc = {0.f, 0.f, 0.f, 0.f};
#pragma unroll
      for (int kk = 0; kk < 4; ++kk) {
        short8 b = *(const short8*)(w1f + ((nt * 4 + kk) * 64 + l) * 8);
        acc = __builtin_amdgcn_mfma_f32_16x16x32_bf16(a1[kk], b, acc, 0, 0, 0);
      }
#pragma unroll
      for (int r = 0; r < 4; ++r) {
        float v = acc[r] + b1v[nt];
        v = v > 0.f ? v : 0.f;
        int row  = q * 4 + r;
        int hcol = nt * 16 + c;
        int eidx = ((hcol >> 5) * 64 + ((hcol >> 3) & 3) * 16 + row) * 8 + (hcol & 7);
        hb[eidx] = (short)f2bf(v);
      }
    }

    short8 a2[4];
#pragma unroll
    for (int kk = 0; kk < 4; ++kk)
      a2[kk] = *(const short8*)(hb + (kk * 64 + l) * 8);
#pragma unroll
    for (int nt = 0; nt < 8; ++nt) {
      floatx4 acc = {0.f, 0.f, 0.f, 0.f};
#pragma unroll
      for (int kk = 0; kk < 4; ++kk) {
        short8 b = *(const short8*)(w2f + ((nt * 4 + kk) * 64 + l) * 8);
        acc = __builtin_amdgcn_mfma_f32_16x16x32_bf16(a2[kk], b, acc, 0, 0, 0);
      }
      float m = fmaxf(fmaxf(acc[0], acc[1]), fmaxf(acc[2], acc[3])) + b2v[nt];
      m = fmaxf(m, __shfl_xor(m, 16, 64));
      m = fmaxf(m, __shfl_xor(m, 32, 64));
      if (q == 0) outf[(size_t)p * 128 + nt * 16 + c] = m;
    }
  }
}
__global__ __launch_bounds__(256) void mlp_kernel(
    const void* x, const void* W1, const void* b1,
    const void* W2, const void* b2, float* outf) {
  __shared__ short w1f[16384];
  __shared__ short w2f[16384];
  __shared__ short hbuf[4][2048];
  if (sniff_bf16(x)) mlp_body<true>(x, W1, b1, W2, b2, outf, w1f, w2f, hbuf);
  else               mlp_body<false>(x, W1, b1, W2, b2, outf, w1f, w2f, hbuf);
}

extern "C" void kernel_launch(void* const* d_in, const int* in_sizes, int n_in,
                              void* d_out, int out_size, void* d_ws, size_t ws_size,
                              hipStream_t stream) {
  const void* x  = d_in[0];
  const void* W1 = d_in[1];
  const void* b1 = d_in[2];
  const void* W2 = d_in[3];
  const void* b2 = d_in[4];
  float* outf = (float*)d_out;
  u16* sqh = (u16*)d_ws;               // 32 KB
  u16* sql = sqh + NP;                 // 32 KB
  u16* xh  = sql + NP;                 // 2 MB
  u16* xl  = xh + (size_t)NP * FD;     // 2 MB   (total ws use: 4.06 MB)

  cvt_kernel  <<<dim3(NP * FD / 8 / 256), dim3(256), 0, stream>>>(x, sqh, sql, xh, xl);
  knn_kernel  <<<dim3(NP / 128, 4),       dim3(256), 0, stream>>>(xh, xl, sqh, sql, outf);
  merge_kernel<<<dim3(NP / 64),           dim3(256), 0, stream>>>(outf);
  mlp_kernel  <<<dim3(1024),              dim3(256), 0, stream>>>(x, W1, b1, W2, b2, outf);
}

// Round 17
// 399.625 us; speedup vs baseline: 1.0177x; 1.0177x over previous
//
#include <hip/hip_runtime.h>
#include <hip/hip_bf16.h>

typedef unsigned short u16;
typedef unsigned int u32;
typedef unsigned long long u64;
typedef __attribute__((ext_vector_type(8))) short short8;
typedef __attribute__((ext_vector_type(8))) _Float16 half8;
typedef __attribute__((ext_vector_type(4))) float floatx4;
typedef __attribute__((ext_vector_type(16))) float floatx16;

#define NP 16384
#define FD 64
#define FLT_BIG 3.0e38f
#define CB 8            // flush threshold (R16 probe: 12 was flat; 8 = R15-proven)
#define CBD 12          // candidate depth (check every 4 pairs: max idx 10)
#define CHUNK 128       // staged columns per chunk

__device__ __forceinline__ float blo(u32 u) {
  u32 v = u << 16; float f; __builtin_memcpy(&f, &v, 4); return f;
}
__device__ __forceinline__ float bhi(u32 u) {
  u32 v = u & 0xffff0000u; float f; __builtin_memcpy(&f, &v, 4); return f;
}
__device__ __forceinline__ float bf2f(u16 u) {
  u32 v = ((u32)u) << 16; float f; __builtin_memcpy(&f, &v, 4); return f;
}
__device__ __forceinline__ u16 f2bf(float f) {
  u32 u; __builtin_memcpy(&u, &f, 4);
  u += 0x7fffu + ((u >> 16) & 1u);
  return (u16)(u >> 16);
}

// runtime input-dtype sniff (confirmed fp32 in earlier rounds; kept for safety)
__device__ __forceinline__ bool sniff_bf16(const void* xg) {
  const u16* p = (const u16*)xg;
  int bad = 0;
#pragma unroll
  for (int t = 0; t < 32; ++t) {
    int e = (p[2 * t] >> 7) & 0xFF;
    bad += (e < 90 || e > 132) ? 1 : 0;
  }
  return bad <= 3;
}

// insert v (known < d[15]) into ascending-sorted 16-array, stable (earlier wins ties)
__device__ __forceinline__ void insert16(float (&d)[16], int (&id)[16], float v, int j) {
#pragma unroll
  for (int t = 15; t >= 1; --t) {
    float a = d[t-1], b = d[t];
    int   ia = id[t-1], ib = id[t];
    bool sh   = v < a;
    bool here = v < b;
    d[t]  = sh ? a  : (here ? v : b);
    id[t] = sh ? ia : (here ? j : ib);
  }
  bool h0 = v < d[0];
  d[0]  = h0 ? v : d[0];
  id[0] = h0 ? j : id[0];
}

// direct global->LDS async copies (dest = wave-uniform base + lane*size).
typedef const __attribute__((address_space(1))) u32 as1_u32;
typedef __attribute__((address_space(3))) u32 as3_u32;
__device__ __forceinline__ void async16(const void* g, void* l) {
  __builtin_amdgcn_global_load_lds((as1_u32*)(u64)g, (as3_u32*)(u32)(u64)l, 16, 0, 0);
}
__device__ __forceinline__ void async4(const void* g, void* l) {
  __builtin_amdgcn_global_load_lds((as1_u32*)(u64)g, (as3_u32*)(u32)(u64)l, 4, 0, 0);
}

// ============ workspace layout (d_ws) ============
// sqh[NP] f16 | sql[NP] f16 | xh[NP*64] f16 | xl[NP*64] f16   (4.0625 MB)
// xh = f16(x); xl = f16((x - xh) * 4096)   (scaled-lo split, near-fp32 dots)
// sqh/sql: same split of the squared norms (folded into MFMA as an extra K-slice).

// ================= K0: convert + norms =================
template<bool BF>
__device__ __forceinline__ void cvt_body(const void* x, u16* sqh, u16* sql,
                                         u16* xh, u16* xl) {
  int t = blockIdx.x * 256 + threadIdx.x;
  int row = t >> 3;
  int e0 = (t & 7) * 8;
  float v[8];
  if (BF) {
    uint4 u = *(const uint4*)((const u16*)x + (size_t)row * FD + e0);
    v[0] = blo(u.x); v[1] = bhi(u.x);
    v[2] = blo(u.y); v[3] = bhi(u.y);
    v[4] = blo(u.z); v[5] = bhi(u.z);
    v[6] = blo(u.w); v[7] = bhi(u.w);
  } else {
    const float4* p = (const float4*)((const float*)x + (size_t)row * FD + e0);
    float4 a = p[0], b = p[1];
    v[0] = a.x; v[1] = a.y; v[2] = a.z; v[3] = a.w;
    v[4] = b.x; v[5] = b.y; v[6] = b.z; v[7] = b.w;
  }
  short8 hv, lv;
  float s = 0.f;
#pragma unroll
  for (int j = 0; j < 8; ++j) {
    _Float16 h = (_Float16)v[j];
    float hf = (float)h;
    _Float16 w2 = (_Float16)((v[j] - hf) * 4096.f);
    u16 hb, lb;
    __builtin_memcpy(&hb, &h, 2);
    __builtin_memcpy(&lb, &w2, 2);
    hv[j] = (short)hb; lv[j] = (short)lb;
    s = fmaf(v[j], v[j], s);
  }
  *(short8*)(xh + (size_t)row * FD + e0) = hv;
  *(short8*)(xl + (size_t)row * FD + e0) = lv;
  s += __shfl_xor(s, 1);
  s += __shfl_xor(s, 2);
  s += __shfl_xor(s, 4);
  if ((t & 7) == 0) {
    _Float16 h = (_Float16)s;
    float hf = (float)h;
    _Float16 w2 = (_Float16)((s - hf) * 4096.f);
    u16 hb, lb;
    __builtin_memcpy(&hb, &h, 2);
    __builtin_memcpy(&lb, &w2, 2);
    sqh[row] = hb; sql[row] = lb;
  }
}
__global__ __launch_bounds__(256) void cvt_kernel(const void* x, u16* sqh, u16* sql,
                                                  u16* xh, u16* xl) {
  if (sniff_bf16(x)) cvt_body<true>(x, sqh, sql, xh, xl);
  else               cvt_body<false>(x, sqh, sql, xh, xl);
}

// flush candidate buffer: wave-max bounded runtime loop (compact code, 1 insert16 copy)
__device__ __forceinline__ void flushbuf(float2* myb, int& cnt,
                                         float (&d16)[16], int (&i16)[16]) {
  int mx = cnt;
#pragma unroll
  for (int o = 1; o < 64; o <<= 1) {
    int om = __shfl_xor(mx, o);
    mx = mx > om ? mx : om;
  }
#pragma unroll 1
  for (int e = 0; e < mx; ++e) {
    float2 v = myb[e * 64];
    float dv = (e < cnt) ? v.x : FLT_BIG;
    if (dv < d16[15]) insert16(d16, i16, dv, __float_as_int(v.y));
  }
  cnt = 0;
}

// selection epilogue for one 32x32 tile; SELF=true only for the diagonal tile
// (wave-row-base == tile-col-base; both 32-aligned so others can't contain self).
// Push is UNCONDITIONAL ds_write to slot cnt (LDS pipe, 2-way bank = free) with
// cnt += p — removes the exec-mask predication from the VALU ledger; non-pushed
// slots are overwritten by the next pair, flush guards with (e < cnt).
template<bool SELF>
__device__ __forceinline__ void epi(const floatx16& acc1, const floatx16& a2a,
                                    const floatx16& a2b, int cb0, int row,
                                    float2* myb, int& cnt,
                                    float (&d16)[16], int (&i16)[16]) {
#pragma unroll
  for (int k = 0; k < 4; ++k) {
#pragma unroll
    for (int r = 0; r < 4; ++r) {
      int t = 4 * k + r;
      // dd = sq_j/2 - dot  (monotone in distance; sq_i dropped as row-constant)
      float d = fmaf(a2a[t] + a2b[t], -2.44140625e-4f, -acc1[t]);
      int col = cb0 + r + 8 * k;
      bool p = (d < d16[15]);
      if (SELF) p = p & (col != row);
      myb[cnt * 64] = make_float2(d, __int_as_float(col));  // unconditional
      cnt += p;
    }
    if (__any(cnt >= CB)) flushbuf(myb, cnt, d16, i16);   // max idx 10 < depth
  }
}

// ======== K1: 4-seg MFMA kNN (R7/R12/R15-proven structure). grid (NP/128, 4) ========
// Per wave: 32 rows; B = row points (regs), A = column points (LDS, 128-col chunks,
// two-barrier staging).  3 MFMA chains (hh+sq -> acc1; h*lo+sql -> a2a; lo*h -> a2b).
// C layout: col=lane&31 -> ROW point; row=(reg&3)+8*(reg>>2)+4*(lane>>5) -> col point.
// LDS k-slot swizzle kc^(col&7) applied on the global source (linear LDS dest).
// launch_bounds(256,2): LDS (57.8KB) caps at 2 blocks/CU anyway -> big VGPR budget;
// unroll 2 of the ct-tiles (R12-proven, 92 VGPR): MFMA chains of tile ct+1 overlap
// epi/flush VALU of tile ct.  (Full unroll = compile blowup, R13/R14.)
__global__ __launch_bounds__(256, 2) void knn_kernel(
    const u16* __restrict__ xh, const u16* __restrict__ xl,
    const u16* __restrict__ sqh, const u16* __restrict__ sql,
    float* __restrict__ outf) {
  __shared__ u16 ch[CHUNK * 64];      // 16 KB  hi chunk (swizzled slots)
  __shared__ u16 cl[CHUNK * 64];      // 16 KB  lo chunk
  __shared__ u16 sqhl[CHUNK];         // 256 B
  __shared__ u16 sqll[CHUNK];         // 256 B
  __shared__ float2 cbuf[4][CBD][64]; // 24 KB  candidate buffers

  int tid = threadIdx.x;
  int w = __builtin_amdgcn_readfirstlane(tid >> 6);
  int l = tid & 63;
  int lo5 = l & 31, hi5 = l >> 5;
  int row = blockIdx.x * 128 + w * 32 + lo5;
  int rowbase = blockIdx.x * 128 + w * 32;
  int seg0 = blockIdx.y * 4096;

  half8 bh[4], bl[4];
  {
    const u16* rp = xh + (size_t)row * FD + hi5 * 8;
    const u16* rq = xl + (size_t)row * FD + hi5 * 8;
#pragma unroll
    for (int q = 0; q < 4; ++q) {
      bh[q] = *(const half8*)(rp + q * 16);
      bl[q] = *(const half8*)(rq + q * 16);
    }
  }
  half8 bx;
#pragma unroll
  for (int j = 0; j < 8; ++j) bx[j] = (_Float16)0.f;
  if (hi5 == 0) bx[0] = (_Float16)(-0.5f);

  float d16[16]; int i16[16];
#pragma unroll
  for (int t = 0; t < 16; ++t) { d16[t] = FLT_BIG; i16[t] = 0; }
  float2* myb = &cbuf[w][0][l];
  int cnt = 0;

#pragma unroll 1
  for (int c = 0; c < 4096 / CHUNK; ++c) {
    int colbase = seg0 + c * CHUNK;
    __syncthreads();
#pragma unroll
    for (int u = 0; u < 4; ++u) {
      int s = (u * 4 + w) * 64 + l;
      int col = s >> 3, kc = s & 7;
      int off = ((colbase + col) << 6) + ((kc ^ (col & 7)) << 3);
      async16(xh + off, &ch[(u * 4 + w) * 512]);
      async16(xl + off, &cl[(u * 4 + w) * 512]);
    }
    if (w == 0) {
      async4((const u32*)(sqh + colbase) + l, &sqhl[0]);
      async4((const u32*)(sql + colbase) + l, &sqll[0]);
    }
    __syncthreads();

#pragma unroll 2
    for (int ct = 0; ct < CHUNK / 32; ++ct) {
      int colA = ct * 32 + lo5;
      int c7 = colA & 7;
      const u16* hp = &ch[colA * 64];
      const u16* lp = &cl[colA * 64];

      half8 ax, axl;
#pragma unroll
      for (int j = 0; j < 8; ++j) { ax[j] = (_Float16)0.f; axl[j] = (_Float16)0.f; }
      {
        u16 shv = sqhl[colA], slv = sqll[colA];
        _Float16 fh, fl2;
        __builtin_memcpy(&fh, &shv, 2);
        __builtin_memcpy(&fl2, &slv, 2);
        if (hi5 == 0) { ax[0] = fh; axl[0] = fl2; }
      }
      floatx16 zz;
#pragma unroll
      for (int t = 0; t < 16; ++t) zz[t] = 0.f;
      floatx16 acc1 = __builtin_amdgcn_mfma_f32_32x32x16_f16(ax,  bx, zz, 0, 0, 0);
      floatx16 a2a  = __builtin_amdgcn_mfma_f32_32x32x16_f16(axl, bx, zz, 0, 0, 0);
      floatx16 a2b  = zz;
#pragma unroll
      for (int q = 0; q < 4; ++q) {
        int so = ((2 * q + hi5) ^ c7) << 3;
        half8 ah = *(const half8*)(hp + so);
        half8 al = *(const half8*)(lp + so);
        acc1 = __builtin_amdgcn_mfma_f32_32x32x16_f16(ah, bh[q], acc1, 0, 0, 0);
        a2a  = __builtin_amdgcn_mfma_f32_32x32x16_f16(ah, bl[q], a2a, 0, 0, 0);
        a2b  = __builtin_amdgcn_mfma_f32_32x32x16_f16(al, bh[q], a2b, 0, 0, 0);
      }
      int cb0 = colbase + ct * 32 + 4 * hi5;
      bool diag = (rowbase == colbase + ct * 32);
      if (diag) epi<true >(acc1, a2a, a2b, cb0, row, myb, cnt, d16, i16);
      else      epi<false>(acc1, a2a, a2b, cb0, row, myb, cnt, d16, i16);
    }
  }
  flushbuf(myb, cnt, d16, i16);

  float od[16]; int oi[16];
#pragma unroll
  for (int t = 0; t < 16; ++t) {
    od[t] = __shfl_xor(d16[t], 32);
    oi[t] = __shfl_xor(i16[t], 32);
  }
#pragma unroll
  for (int t = 0; t < 16; ++t)
    if (od[t] < d16[15]) insert16(d16, i16, od[t], oi[t]);

  if (hi5 == 0) {
    float2* op = (float2*)outf + (size_t)row * 64 + blockIdx.y * 16;
#pragma unroll
    for (int t = 0; t < 8; ++t) {
      float4 v4 = make_float4(d16[2*t],   __int_as_float(i16[2*t]),
                              d16[2*t+1], __int_as_float(i16[2*t+1]));
      *(float4*)(op + 2 * t) = v4;
    }
  }
}

// ======== K2: merge 4 segment partials -> final 16 ids (record ints [0..15]) ========
// 4 lanes per point: own seg's sorted 16 copied, then 2 shfl-merge rounds;
// seg-ascending combine preserves stable ties (strict-<).
__global__ __launch_bounds__(256) void merge_kernel(float* outf) {
  int tid = threadIdx.x;
  int p = blockIdx.x * 64 + (tid >> 2);
  int sub = tid & 3;
  const float2* cp = (const float2*)outf + (size_t)p * 64 + sub * 16;
  float d16[16]; int i16[16];
#pragma unroll
  for (int t = 0; t < 16; ++t) {
    float2 v = cp[t];
    d16[t] = v.x; i16[t] = __float_as_int(v.y);
  }
#pragma unroll
  for (int rnd = 0; rnd < 2; ++rnd) {
    int dx = 1 << rnd;
    float od[16]; int oi[16];
#pragma unroll
    for (int t = 0; t < 16; ++t) {
      od[t] = __shfl_xor(d16[t], dx);
      oi[t] = __shfl_xor(i16[t], dx);
    }
#pragma unroll
    for (int t = 0; t < 16; ++t)
      if (od[t] < d16[15]) insert16(d16, i16, od[t], oi[t]);
  }
  if (sub == 0) {
    int* op = (int*)outf + (size_t)p * 128;
#pragma unroll
    for (int t = 0; t < 16; ++t) op[t] = i16[t];
  }
}

// ================= K3: edge MLP + max aggregation (MFMA, bf16 compute) =================
// A-frag 16x16x32: lane holds A[m=l&15][k=(l>>4)*8+j].  C/D: col=l&15, row=(l>>4)*4+reg.
// grid 1024 blocks to hide the random neighbor gathers; fp32 gathers via float4.
template<bool BF>
__device__ __forceinline__ void mlp_body(
    const void* x, const void* W1, const void* b1,
    const void* W2, const void* b2, float* outf,
    short* w1f, short* w2f, short (*hbuf)[2048]) {
  int tid = threadIdx.x;
  for (int s2 = tid; s2 < 4096; s2 += 256) {
    int which = s2 >> 11, t = s2 & 2047;
    int frag = t >> 6, lane = t & 63;
    int nt = frag >> 2, kk = frag & 3;
    int n  = nt * 16 + (lane & 15);
    int kb = kk * 32 + ((lane >> 4) * 8);
    short8 v;
    if (BF) {
      const u16* W = (const u16*)(which ? W2 : W1);
#pragma unroll
      for (int j = 0; j < 8; ++j) v[j] = (short)W[(size_t)(kb + j) * 128 + n];
    } else {
      const float* W = (const float*)(which ? W2 : W1);
#pragma unroll
      for (int j = 0; j < 8; ++j) v[j] = (short)f2bf(W[(size_t)(kb + j) * 128 + n]);
    }
    *(short8*)((which ? w2f : w1f) + t * 8) = v;
  }
  __syncthreads();

  int l = tid & 63, w = tid >> 6;
  int q = l >> 4, c = l & 15;
  short* hb = hbuf[w];

  float b1v[8], b2v[8];
#pragma unroll
  for (int nt = 0; nt < 8; ++nt) {
    b1v[nt] = BF ? bf2f(((const u16*)b1)[nt * 16 + c]) : ((const float*)b1)[nt * 16 + c];
    b2v[nt] = BF ? bf2f(((const u16*)b2)[nt * 16 + c]) : ((const float*)b2)[nt * 16 + c];
  }

  int wid = blockIdx.x * 4 + w;
  for (int p = wid; p < NP; p += 4096) {
    int nb = ((const int*)outf)[(size_t)p * 128 + c] & (NP - 1);
    short8 a1[4];
    if (BF) {
      const short* xp  = (const short*)x + (size_t)p  * FD;
      const short* xnp = (const short*)x + (size_t)nb * FD;
      a1[0] = *(const short8*)(xp + q * 8);
      a1[1] = *(const short8*)(xp + 32 + q * 8);
#pragma unroll
      for (int kk = 2; kk < 4; ++kk) {
        int kb = (kk - 2) * 32 + q * 8;
        short8 xi8 = *(const short8*)(xp + kb);
        short8 xj8 = *(const short8*)(xnp + kb);
        short8 dfr;
#pragma unroll
        for (int j = 0; j < 8; ++j)
          dfr[j] = (short)f2bf(bf2f((u16)xj8[j]) - bf2f((u16)xi8[j]));
        a1[kk] = dfr;
      }
    } else {
      const float* xp  = (const float*)x + (size_t)p  * FD + q * 8;
      const float* xnp = (const float*)x + (size_t)nb * FD + q * 8;
      float4 pi0 = *(const float4*)(xp);
      float4 pi1 = *(const float4*)(xp + 4);
      float4 pj0 = *(const float4*)(xp + 32);
      float4 pj1 = *(const float4*)(xp + 36);
      float4 ni0 = *(const float4*)(xnp);
      float4 ni1 = *(const float4*)(xnp + 4);
      float4 nj0 = *(const float4*)(xnp + 32);
      float4 nj1 = *(const float4*)(xnp + 36);
      float xi0a[8] = {pi0.x, pi0.y, pi0.z, pi0.w, pi1.x, pi1.y, pi1.z, pi1.w};
      float xi1a[8] = {pj0.x, pj0.y, pj0.z, pj0.w, pj1.x, pj1.y, pj1.z, pj1.w};
      float xn0a[8] = {ni0.x, ni0.y, ni0.z, ni0.w, ni1.x, ni1.y, ni1.z, ni1.w};
      float xn1a[8] = {nj0.x, nj0.y, nj0.z, nj0.w, nj1.x, nj1.y, nj1.z, nj1.w};
#pragma unroll
      for (int j = 0; j < 8; ++j) {
        a1[0][j] = (short)f2bf(xi0a[j]);
        a1[1][j] = (short)f2bf(xi1a[j]);
        a1[2][j] = (short)f2bf(xn0a[j] - xi0a[j]);
        a1[3][j] = (short)f2bf(xn1a[j] - xi1a[j]);
      }
    }

#pragma unroll
    for (int nt = 0; nt < 8; ++nt) {
      floatx4 acc = {0.f, 0.f, 0.f, 0.f};
#pragma unroll
      for (int kk = 0; kk < 4; ++kk) {
        short8 b = *(const short8*)(w1f + ((nt * 4 + kk) * 64 + l) * 8);
        acc = __builtin_amdgcn_mfma_f32_16x16x32_bf16(a1[kk], b, acc, 0, 0, 0);
      }
#pragma unroll
      for (int r = 0; r < 4; ++r) {
        float v = acc[r] + b1v[nt];
        v = v > 0.f ? v : 0.f;
        int row  = q * 4 + r;
        int hcol = nt * 16 + c;
        int eidx = ((hcol >> 5) * 64 + ((hcol >> 3) & 3) * 16 + row) * 8 + (hcol & 7);
        hb[eidx] = (short)f2bf(v);
      }
    }

    short8 a2[4];
#pragma unroll
    for (int kk = 0; kk < 4; ++kk)
      a2[kk] = *(const short8*)(hb + (kk * 64 + l) * 8);
#pragma unroll
    for (int nt = 0; nt < 8; ++nt) {
      floatx4 acc = {0.f, 0.f, 0.f, 0.f};
#pragma unroll
      for (int kk = 0; kk < 4; ++kk) {
        short8 b = *(const short8*)(w2f + ((nt * 4 + kk) * 64 + l) * 8);
        acc = __builtin_amdgcn_mfma_f32_16x16x32_bf16(a2[kk], b, acc, 0, 0, 0);
      }
      float m = fmaxf(fmaxf(acc[0], acc[1]), fmaxf(acc[2], acc[3])) + b2v[nt];
      m = fmaxf(m, __shfl_xor(m, 16, 64));
      m = fmaxf(m, __shfl_xor(m, 32, 64));
      if (q == 0) outf[(size_t)p * 128 + nt * 16 + c] = m;
    }
  }
}
__global__ __launch_bounds__(256) void mlp_kernel(
    const void* x, const void* W1, const void* b1,
    const void* W2, const void* b2, float* outf) {
  __shared__ short w1f[16384];
  __shared__ short w2f[16384];
  __shared__ short hbuf[4][2048];
  if (sniff_bf16(x)) mlp_body<true>(x, W1, b1, W2, b2, outf, w1f, w2f, hbuf);
  else               mlp_body<false>(x, W1, b1, W2, b2, outf, w1f, w2f, hbuf);
}

extern "C" void kernel_launch(void* const* d_in, const int* in_sizes, int n_in,
                              void* d_out, int out_size, void* d_ws, size_t ws_size,
                              hipStream_t stream) {
  const void* x  = d_in[0];
  const void* W1 = d_in[1];
  const void* b1 = d_in[2];
  const void* W2 = d_in[3];
  const void* b2 = d_in[4];
  float* outf = (float*)d_out;
  u16* sqh = (u16*)d_ws;               // 32 KB
  u16* sql = sqh + NP;                 // 32 KB
  u16* xh  = sql + NP;                 // 2 MB
  u16* xl  = xh + (size_t)NP * FD;     // 2 MB   (total ws use: 4.06 MB)

  cvt_kernel  <<<dim3(NP * FD / 8 / 256), dim3(256), 0, stream>>>(x, sqh, sql, xh, xl);
  knn_kernel  <<<dim3(NP / 128, 4),       dim3(256), 0, stream>>>(xh, xl, sqh, sql, outf);
  merge_kernel<<<dim3(NP / 64),           dim3(256), 0, stream>>>(outf);
  mlp_kernel  <<<dim3(1024),              dim3(256), 0, stream>>>(x, W1, b1, W2, b2, outf);
}